// Round 7
// baseline (612.862 us; speedup 1.0000x reference)
//
#include <hip/hip_runtime.h>
#include <math.h>

#define B_   4
#define T_   2048
#define D_   512
#define TOK  (B_*T_)      // 8192 tokens
#define TL_  2045         // N_BLOCKS*(T//N_BLOCKS) = 5*409
#define GATE 0.2f         // softmax(...).mean(-1) over same axis == 1/5
#define QSCALE 0.18033688011112043f   // 0.125 * log2(e): S in log2 domain

typedef unsigned short u16;
typedef __attribute__((ext_vector_type(8))) short short8;   // 8 bf16 = 4 VGPRs
typedef __attribute__((ext_vector_type(4))) float f32x4;

static __device__ __forceinline__ u16 f2u(float f){      // fp32 -> bf16 (RNE)
    union { float f; unsigned u; } a; a.f = f;
    unsigned r = a.u + 0x7fffu + ((a.u >> 16) & 1u);
    return (u16)(r >> 16);
}
static __device__ __forceinline__ float u2f(u16 u){
    union { unsigned u; float f; } a; a.u = ((unsigned)u) << 16;
    return a.f;
}
static __device__ __forceinline__ f32x4 mfma16(short8 a, short8 b, f32x4 c){
    return __builtin_amdgcn_mfma_f32_16x16x32_bf16(a, b, c, 0, 0, 0);
}
static __device__ __forceinline__ void glds16(const u16* g, u16* l){
    __builtin_amdgcn_global_load_lds((const __attribute__((address_space(1))) void*)g,
                                     (__attribute__((address_space(3))) void*)l, 16, 0, 0);
}

// ------------------------------------------------------------------
// gate + pool fused: XFcat[:,0:512]=bf16(0.2*x masked), XFcat[:,512:]=bf16(pool)
__global__ __launch_bounds__(256) void gatepool_kernel(
    const float* __restrict__ x, u16* __restrict__ xfcat)
{
    int idx = blockIdx.x*256 + threadIdx.x;
    int d = idx & 511, g = idx >> 9;
    int b = g >> 7, t0 = (g & 127) << 4;
    const float* xp = x + ((size_t)b*2048)*512 + d;
    float v[30];
    #pragma unroll
    for (int j = 0; j < 30; ++j){
        int u = t0 - 7 + j;
        v[j] = (u >= 0 && u < TL_) ? xp[(size_t)u*512] : 0.f;
    }
    float p[31]; p[0] = 0.f;
    #pragma unroll
    for (int j = 0; j < 30; ++j) p[j+1] = p[j] + v[j];
    u16* xc = xfcat + ((size_t)(b*2048 + t0))*1024 + d;
    #pragma unroll
    for (int i = 0; i < 16; ++i){
        int t = t0 + i;
        float sum = p[i+15] - p[i];                 // u in [t-7, t+7]
        int lo = t-7; if (lo < 0) lo = 0;
        int hi = t+7; if (hi > 2047) hi = 2047;
        xc[(size_t)i*1024]       = f2u((t < TL_) ? GATE*v[i+7] : 0.f);
        xc[(size_t)i*1024 + 512] = f2u(GATE * sum / (float)(hi - lo + 1));
    }
}

// ------------------------------------------------------------------
// batched transpose+convert: src fp32 [K,N] -> dst[n*ldout+coloff+k]=bf16(scale*src)
struct TJob { const float* src; u16* dst; int K, N, ldout, coloff, tiles; float scale; };
struct TJobs { TJob j[13]; int n; };

__global__ __launch_bounds__(256) void tconv_all_kernel(TJobs JJ){
    __shared__ float t[32][33];
    int idx = blockIdx.x;
    int jb = 0;
    while (jb < JJ.n - 1 && idx >= JJ.j[jb].tiles){ idx -= JJ.j[jb].tiles; ++jb; }
    TJob J = JJ.j[jb];
    int tX = J.N >> 5;
    int k0 = (idx / tX) * 32, n0 = (idx % tX) * 32;
    int tx = threadIdx.x & 31, ty = threadIdx.x >> 5;
    #pragma unroll
    for (int i = 0; i < 32; i += 8)
        t[ty+i][tx] = J.src[(size_t)(k0+ty+i)*J.N + n0+tx];
    __syncthreads();
    #pragma unroll
    for (int i = 0; i < 32; i += 8)
        J.dst[(size_t)(n0+ty+i)*J.ldout + J.coloff + k0+tx] = f2u(J.scale * t[tx][ty+i]);
}

// fp32 -> bf16 plain convert
__global__ void convert_kernel(const float* __restrict__ in, u16* __restrict__ out){
    int idx = blockIdx.x*256 + threadIdx.x;
    out[idx] = f2u(in[idx]);
}

// fubias[n] = fu_b[n] + sum_d mp_b[d] * fu_w[512+d][n]
__global__ __launch_bounds__(256) void biasfold_kernel(
    const float* __restrict__ fu_b, const float* __restrict__ mp_b,
    const float* __restrict__ fu_w, float* __restrict__ out)
{
    int n = blockIdx.x, tid = threadIdx.x;
    float s = mp_b[tid]*fu_w[(size_t)(512+tid)*512 + n]
            + mp_b[tid+256]*fu_w[(size_t)(768+tid)*512 + n];
    for (int off = 32; off; off >>= 1) s += __shfl_down(s, off);
    __shared__ float ws[4];
    if ((tid & 63) == 0) ws[tid >> 6] = s;
    __syncthreads();
    if (tid == 0) out[n] = fu_b[n] + ws[0]+ws[1]+ws[2]+ws[3];
}

// qkvbias[n] = sum_d fubias[d] * wqkvT[n][d]   (wqkvT rows contiguous, len 512)
__global__ __launch_bounds__(256) void qkvbias_kernel(
    const float* __restrict__ fubias, const u16* __restrict__ wqkvT,
    float* __restrict__ out)
{
    int n = blockIdx.x, tid = threadIdx.x;
    const u16* wp = wqkvT + (size_t)n*512;
    float s = fubias[tid]*u2f(wp[tid]) + fubias[tid+256]*u2f(wp[tid+256]);
    for (int off = 32; off; off >>= 1) s += __shfl_down(s, off);
    __shared__ float ws[4];
    if ((tid & 63) == 0) ws[tid >> 6] = s;
    __syncthreads();
    if (tid == 0) out[n] = ws[0]+ws[1]+ws[2]+ws[3];
}

// small fp32 GEMM, N=512, writes bf16 TRANSPOSED: dstT[n*512 + m] = (A@B)[m][n]
__global__ __launch_bounds__(256) void sgemm_kernel(const float* __restrict__ A,
    const float* __restrict__ B, u16* __restrict__ dstT, int K){
    __shared__ float As[16][65];
    __shared__ float Bs[16][65];
    int tid = threadIdx.x;
    int tx = tid & 15, ty = tid >> 4;
    int m0 = blockIdx.y*64, n0 = blockIdx.x*64;
    int arow = tid >> 2, akq = (tid & 3) * 4;
    int bk = tid >> 4, bn = (tid & 15) * 4;
    float acc[4][4] = {};
    for (int k0 = 0; k0 < K; k0 += 16){
        const float* Ap = A + (size_t)(m0+arow)*K + k0 + akq;
        As[akq+0][arow]=Ap[0]; As[akq+1][arow]=Ap[1];
        As[akq+2][arow]=Ap[2]; As[akq+3][arow]=Ap[3];
        const float* Bp = B + (size_t)(k0+bk)*512 + n0 + bn;
        Bs[bk][bn+0]=Bp[0]; Bs[bk][bn+1]=Bp[1];
        Bs[bk][bn+2]=Bp[2]; Bs[bk][bn+3]=Bp[3];
        __syncthreads();
        #pragma unroll
        for (int kk = 0; kk < 16; ++kk){
            float av[4], bv[4];
            #pragma unroll
            for (int i=0;i<4;++i) av[i]=As[kk][ty*4+i];
            #pragma unroll
            for (int j=0;j<4;++j) bv[j]=Bs[kk][tx*4+j];
            #pragma unroll
            for (int i=0;i<4;++i)
                #pragma unroll
                for (int j=0;j<4;++j) acc[i][j] += av[i]*bv[j];
        }
        __syncthreads();
    }
    #pragma unroll
    for (int i=0;i<4;++i)
        #pragma unroll
        for (int j=0;j<4;++j)
            dstT[(size_t)(n0+tx*4+j)*512 + m0+ty*4+i] = f2u(acc[i][j]);
}

// ------------------------------------------------------------------
// bf16 MFMA GEMM: C[M,N] = op(A[M,K] @ Bt[N,K]^T + bias), MTx128 tile, BK=64.
#define GF_GELU   1
#define GF_RSCOL  4
#define GF_GLU    8
#define GF_QKV    32   // n0<1024: plain bf16 -> Cp; n0>=1024: bias + transposed -> Cp2

template<int MT>
__global__ __launch_bounds__(256) void mgemm_kernel(
    const u16* __restrict__ A, int lda, const u16* __restrict__ Bt, int ldb,
    const float* __restrict__ bias, const float* __restrict__ rs,
    const u16* __restrict__ glu, void* __restrict__ Cp, int ldc,
    u16* __restrict__ Cp2, int K, int flags)
{
    constexpr int MI = MT/32;            // m-tiles per wave (16 rows each)
    __shared__ u16 As[MT*64];
    __shared__ u16 Bs[128*64];
    int tid = threadIdx.x;
    int wave = tid >> 6, lane = tid & 63;
    int n16 = lane & 15, quad = lane >> 4;
    int m0 = blockIdx.y * MT, n0 = blockIdx.x * 128;
    int wr = (wave >> 1) * (MT/2), wc = (wave & 1) * 64;

    f32x4 acc[MI][4] = {};

    for (int k0 = 0; k0 < K; k0 += 64){
        #pragma unroll
        for (int i = 0; i < MT/32; ++i){
            int s = i*256 + tid;
            int row = s >> 3, g = (s & 7) ^ (row & 7);
            glds16(A + (size_t)(m0+row)*lda + k0 + g*8, As + (size_t)s*8);
        }
        #pragma unroll
        for (int i = 0; i < 4; ++i){
            int s = i*256 + tid;
            int row = s >> 3, g = (s & 7) ^ (row & 7);
            glds16(Bt + (size_t)(n0+row)*ldb + k0 + g*8, Bs + (size_t)s*8);
        }
        __syncthreads();
        #pragma unroll
        for (int ks = 0; ks < 2; ++ks){
            short8 af[MI], bf[4];
            #pragma unroll
            for (int mi = 0; mi < MI; ++mi){
                int row = wr + mi*16 + n16;
                int g = (ks*4 + quad) ^ (row & 7);
                af[mi] = *(const short8*)&As[row*64 + g*8];
            }
            #pragma unroll
            for (int ni = 0; ni < 4; ++ni){
                int row = wc + ni*16 + n16;
                int g = (ks*4 + quad) ^ (row & 7);
                bf[ni] = *(const short8*)&Bs[row*64 + g*8];
            }
            #pragma unroll
            for (int mi = 0; mi < MI; ++mi)
                #pragma unroll
                for (int ni = 0; ni < 4; ++ni)
                    acc[mi][ni] = mfma16(af[mi], bf[ni], acc[mi][ni]);
        }
        __syncthreads();
    }

    if ((flags & GF_QKV) && n0 >= 1024){
        // V region: bias + store transposed into Cp2 [512, 8192]
        #pragma unroll
        for (int mi = 0; mi < MI; ++mi){
            int row0 = m0 + wr + mi*16 + quad*4;
            #pragma unroll
            for (int ni = 0; ni < 4; ++ni){
                int col = n0 + wc + ni*16 + n16;
                float bb = bias[col];
                ushort4 h4;
                h4.x = f2u(acc[mi][ni][0] + bb); h4.y = f2u(acc[mi][ni][1] + bb);
                h4.z = f2u(acc[mi][ni][2] + bb); h4.w = f2u(acc[mi][ni][3] + bb);
                *(ushort4*)&Cp2[(size_t)(col-1024)*8192 + row0] = h4;
            }
        }
        return;
    }

    #pragma unroll
    for (int mi = 0; mi < MI; ++mi){
        #pragma unroll
        for (int reg = 0; reg < 4; ++reg){
            int row = m0 + wr + mi*16 + quad*4 + reg;
            #pragma unroll
            for (int ni = 0; ni < 4; ++ni){
                int col = n0 + wc + ni*16 + n16;
                float v = acc[mi][ni][reg];
                if (bias) v += bias[col];
                if (flags & GF_GELU)  v = 0.5f*v*(1.f + erff(v*0.70710678118f));
                if (flags & GF_GLU)   v = u2f(glu[(size_t)row*512 + col]) / (1.f + __expf(-v));
                if (flags & GF_RSCOL) v *= rs[(size_t)row*4 + (col >> 10)];
                ((u16*)Cp)[(size_t)row*ldc + col] = f2u(v);
            }
        }
    }
}

// ------------------------------------------------------------------
// MFMA flash attention (S^T formulation), causal, dh=64, 8 heads. (unchanged r6)
__global__ __launch_bounds__(256) void flash_kernel(
    const u16* __restrict__ QK,   // [8192,1024]: cols 0..511 Q', 512..1023 K
    const u16* __restrict__ VT,   // [512,8192]
    u16* __restrict__ O)          // [8192,512]
{
    int bid = blockIdx.x;
    int qt = 15 - (bid >> 5);          // global heavy-first
    int bh = bid & 31;
    int h = bh & 7, b = bh >> 3;
    __shared__ u16 Ks[64*64];
    __shared__ u16 Vt[64*64];
    __shared__ u16 Ps[4][32*64];
    int tid = threadIdx.x;
    int wave = tid >> 6, lane = tid & 63;
    int n16 = lane & 15, quad = lane >> 4;
    size_t btok = (size_t)b*2048;
    size_t tok0 = btok + qt*128;

    short8 qf[2][2];
    #pragma unroll
    for (int g = 0; g < 2; ++g)
        #pragma unroll
        for (int ks = 0; ks < 2; ++ks)
            qf[g][ks] = *(const short8*)&QK[(tok0 + wave*32 + g*16 + n16)*1024
                                           + h*64 + ks*32 + quad*8];

    int qlo[2];  qlo[0] = qt*128 + wave*32; qlo[1] = qlo[0] + 16;
    int qrow[2]; qrow[0] = qlo[0] + n16;    qrow[1] = qlo[1] + n16;
    float m_st[2] = {-3.0e38f, -3.0e38f}, l_st[2] = {0.f, 0.f};
    f32x4 ov[2][4] = {};

    int nkt = 2*qt + 2;
    for (int kt = 0; kt < nkt; ++kt){
        __syncthreads();
        {
            int r = tid >> 2;
            int g0 = (tid & 3) * 2;
            const uint4* kp = (const uint4*)&QK[(btok + kt*64 + r)*1024 + 512 + h*64 + g0*8];
            uint4 ka = kp[0], kb = kp[1];
            *(uint4*)&Ks[r*64 + ((g0  ) ^ (r&7))*8] = ka;
            *(uint4*)&Ks[r*64 + ((g0+1) ^ (r&7))*8] = kb;
            const uint4* vp = (const uint4*)&VT[(size_t)(h*64 + r)*8192 + btok + kt*64 + g0*8];
            uint4 va = vp[0], vb = vp[1];
            *(uint4*)&Vt[r*64 + ((g0  ) ^ (r&7))*8] = va;
            *(uint4*)&Vt[r*64 + ((g0+1) ^ (r&7))*8] = vb;
        }
        __syncthreads();

        bool act[2];
        #pragma unroll
        for (int g = 0; g < 2; ++g){
            act[g] = (kt*64 <= qlo[g] + 15);
            if (!act[g]) continue;
            f32x4 st[4];
            #pragma unroll
            for (int ct = 0; ct < 4; ++ct){
                f32x4 a = {};
                #pragma unroll
                for (int ks = 0; ks < 2; ++ks){
                    short8 kf = *(const short8*)&Ks[(ct*16+n16)*64 + (((ks*4+quad) ^ (n16&7))*8)];
                    a = mfma16(kf, qf[g][ks], a);
                }
                st[ct] = a;
            }
            if (kt*64 + 63 > qlo[g]){
                #pragma unroll
                for (int ct = 0; ct < 4; ++ct){
                    int kb0 = kt*64 + ct*16 + quad*4;
                    #pragma unroll
                    for (int r = 0; r < 4; ++r)
                        if (kb0 + r > qrow[g]) st[ct][r] = -3.0e38f;
                }
            }
            float mx = fmaxf(fmaxf(fmaxf(st[0][0],st[0][1]),fmaxf(st[0][2],st[0][3])),
                       fmaxf(fmaxf(fmaxf(st[1][0],st[1][1]),fmaxf(st[1][2],st[1][3])),
                       fmaxf(fmaxf(fmaxf(st[2][0],st[2][1]),fmaxf(st[2][2],st[2][3])),
                             fmaxf(fmaxf(st[3][0],st[3][1]),fmaxf(st[3][2],st[3][3])))));
            mx = fmaxf(mx, __shfl_xor(mx, 16));
            mx = fmaxf(mx, __shfl_xor(mx, 32));
            float mn = fmaxf(m_st[g], mx);
            float al = exp2f(m_st[g] - mn);
            m_st[g] = mn;
            float sum = 0.f;
            #pragma unroll
            for (int ct = 0; ct < 4; ++ct)
                #pragma unroll
                for (int r = 0; r < 4; ++r){
                    float p = exp2f(st[ct][r] - mn);
                    st[ct][r] = p; sum += p;
                }
            sum += __shfl_xor(sum, 16);
            sum += __shfl_xor(sum, 32);
            l_st[g] = l_st[g]*al + sum;
            int qr = g*16 + n16;
            #pragma unroll
            for (int ct = 0; ct < 4; ++ct){
                ushort4 h4;
                h4.x = f2u(st[ct][0]); h4.y = f2u(st[ct][1]);
                h4.z = f2u(st[ct][2]); h4.w = f2u(st[ct][3]);
                int goff = ct*2 + (quad >> 1);
                *(ushort4*)&Ps[wave][qr*64 + ((goff ^ (qr&7))*8) + (quad&1)*4] = h4;
            }
            #pragma unroll
            for (int r = 0; r < 4; ++r){
                float aa = __shfl(al, quad*4 + r);
                #pragma unroll
                for (int dt = 0; dt < 4; ++dt) ov[g][dt][r] *= aa;
            }
        }
        #pragma unroll
        for (int g = 0; g < 2; ++g){
            if (!act[g]) continue;
            short8 ap[2];
            int row = g*16 + n16;
            #pragma unroll
            for (int ks = 0; ks < 2; ++ks)
                ap[ks] = *(const short8*)&Ps[wave][row*64 + (((ks*4+quad) ^ (row&7))*8)];
            #pragma unroll
            for (int dt = 0; dt < 4; ++dt)
                #pragma unroll
                for (int ks = 0; ks < 2; ++ks){
                    short8 bv = *(const short8*)&Vt[(dt*16+n16)*64 + (((ks*4+quad) ^ (n16&7))*8)];
                    ov[g][dt] = mfma16(ap[ks], bv, ov[g][dt]);
                }
        }
    }
    #pragma unroll
    for (int g = 0; g < 2; ++g)
        #pragma unroll
        for (int r = 0; r < 4; ++r){
            float li = __shfl(l_st[g], quad*4 + r);
            float inv = 1.f / li;
            size_t row = tok0 + wave*32 + g*16 + quad*4 + r;
            #pragma unroll
            for (int dt = 0; dt < 4; ++dt)
                O[row*512 + h*64 + dt*16 + n16] = f2u(ov[g][dt][r] * inv);
        }
}

// ------------------------------------------------------------------
// x1h = bf16( rmsnorm(x + y_bf16) * scale )
__global__ __launch_bounds__(256) void rmsnorm_kernel(
    const float* __restrict__ x, const u16* __restrict__ y,
    const float* __restrict__ scale, u16* __restrict__ out)
{
    int tok = blockIdx.x, tid = threadIdx.x;
    size_t base = (size_t)tok * 512;
    float v0 = x[base+tid]     + u2f(y[base+tid]);
    float v1 = x[base+tid+256] + u2f(y[base+tid+256]);
    float ss = v0*v0 + v1*v1;
    for (int off = 32; off; off >>= 1) ss += __shfl_down(ss, off);
    __shared__ float ws[4];
    if ((tid & 63) == 0) ws[tid >> 6] = ss;
    __syncthreads();
    float rstd = rsqrtf((ws[0]+ws[1]+ws[2]+ws[3])*(1.f/512.f) + 1e-6f);
    out[base+tid]     = f2u(scale[tid]     * v0 * rstd);
    out[base+tid+256] = f2u(scale[tid+256] * v1 * rstd);
}

// out_fp32 = rmsnorm(x1h + moe_bf16 + ROUT@b2) * scale
__global__ __launch_bounds__(256) void final_kernel(
    const u16* __restrict__ x1, const u16* __restrict__ moe,
    const float* __restrict__ rout, const float* __restrict__ b2,
    const float* __restrict__ scale, float* __restrict__ out)
{
    int tok = blockIdx.x, tid = threadIdx.x;
    size_t base = (size_t)tok * 512;
    float r0 = rout[tok*4+0], r1 = rout[tok*4+1], r2 = rout[tok*4+2], r3 = rout[tok*4+3];
    float bb0 = r0*b2[tid]     + r1*b2[512+tid]     + r2*b2[1024+tid]     + r3*b2[1536+tid];
    float bb1 = r0*b2[tid+256] + r1*b2[768+tid]     + r2*b2[1280+tid]     + r3*b2[1792+tid];
    float v0 = u2f(x1[base+tid])     + u2f(moe[base+tid])     + bb0;
    float v1 = u2f(x1[base+tid+256]) + u2f(moe[base+tid+256]) + bb1;
    float ss = v0*v0 + v1*v1;
    for (int off = 32; off; off >>= 1) ss += __shfl_down(ss, off);
    __shared__ float ws[4];
    if ((tid & 63) == 0) ws[tid >> 6] = ss;
    __syncthreads();
    float rstd = rsqrtf((ws[0]+ws[1]+ws[2]+ws[3])*(1.f/512.f) + 1e-6f);
    out[base+tid]     = scale[tid]     * v0 * rstd;
    out[base+tid+256] = scale[tid+256] * v1 * rstd;
}

// router: softmax(x1h @ wr + br), one wave per token
__global__ __launch_bounds__(256) void router_kernel(
    const u16* __restrict__ x1, const float* __restrict__ wr,
    const float* __restrict__ br, float* __restrict__ rout)
{
    int wid = threadIdx.x >> 6, lane = threadIdx.x & 63;
    int tok = blockIdx.x*4 + wid;
    const u16* xp = x1 + (size_t)tok*512;
    float p0=0.f, p1=0.f, p2=0.f, p3=0.f;
    for (int d = lane; d < 512; d += 64){
        float xv = u2f(xp[d]);
        p0 += xv*wr[d*4+0]; p1 += xv*wr[d*4+1];
        p2 += xv*wr[d*4+2]; p3 += xv*wr[d*4+3];
    }
    for (int off = 32; off; off >>= 1){
        p0 += __shfl_down(p0,off); p1 += __shfl_down(p1,off);
        p2 += __shfl_down(p2,off); p3 += __shfl_down(p3,off);
    }
    if (lane == 0){
        p0 += br[0]; p1 += br[1]; p2 += br[2]; p3 += br[3];
        float mx = fmaxf(fmaxf(p0,p1), fmaxf(p2,p3));
        float e0=__expf(p0-mx), e1=__expf(p1-mx), e2=__expf(p2-mx), e3=__expf(p3-mx);
        float inv = 1.f/(e0+e1+e2+e3);
        rout[tok*4+0]=e0*inv; rout[tok*4+1]=e1*inv;
        rout[tok*4+2]=e2*inv; rout[tok*4+3]=e3*inv;
    }
}

// ------------------------------------------------------------------
extern "C" void kernel_launch(void* const* d_in, const int* in_sizes, int n_in,
                              void* d_out, int out_size, void* d_ws, size_t ws_size,
                              hipStream_t stream)
{
    const float* x    = (const float*)d_in[0];
    const float* mp_w = (const float*)d_in[3];
    const float* mp_b = (const float*)d_in[4];
    const float* fu_w = (const float*)d_in[5];
    const float* fu_b = (const float*)d_in[6];
    const float* wc   = (const float*)d_in[7];
    const float* wk   = (const float*)d_in[8];
    const float* wv   = (const float*)d_in[9];
    const float* wq   = (const float*)d_in[10];
    const float* wo   = (const float*)d_in[11];
    const float* s1   = (const float*)d_in[12];
    const float* s2   = (const float*)d_in[13];
    const float* wr   = (const float*)d_in[14];
    const float* br   = (const float*)d_in[15];
    const float* wg   = (const float*)d_in[16];
    const float* bg   = (const float*)d_in[17];
    const float* w1   = (const float*)d_in[18];
    const float* b1   = (const float*)d_in[19];
    const float* w2   = (const float*)d_in[20];
    const float* b2   = (const float*)d_in[21];

    char* wsb = (char*)d_ws;
    const size_t MB = 1024*1024;
    // persistent-live (0..12.5 MB)
    u16*   WqkvC  = (u16*)(wsb + 0);                 // [1536,1024] combined Wfu_eff@Wqkv, ^T
    u16*   woT    = (u16*)(wsb + 3*MB);              // [512,512]
    u16*   wgT    = (u16*)(wsb + 3*MB + 512*1024);   // [512,512]
    u16*   w1T    = (u16*)(wsb + 4*MB);              // [4096,512] all experts
    u16*   w2Ts   = (u16*)(wsb + 8*MB);              // [512,4096] all experts
    float* fubias = (float*)(wsb + 12*MB);           // 512
    float* qkvbias= (float*)(wsb + 12*MB + 4096);    // 1536
    float* ROUT   = (float*)(wsb + 12*MB + 16384);   // 8192x4
    // prepass scratch (dead before gatepool)
    u16*   wqkvT  = (u16*)(wsb + 25*MB/2);           // [1536,512]: wq' | wc@wk | wc@wv
    u16*   fuBT   = (u16*)(wsb + 14*MB);             // [512,512] (fuB)^T
    u16*   mp_wB  = (u16*)(wsb + 29*MB/2);           // [512,512] row-major bf16
    u16*   WfuBF  = (u16*)(wsb + 15*MB);             // [1024,512] Wfu_eff row-major bf16
    // big rotating buffers (high-water 72 MB)
    u16*   XFcat = (u16*)(wsb + 16*MB);              // [8192,1024]; dead after QKV
    u16*   S3    = (u16*)(wsb + 16*MB);              // [8192,512] wo out; dead after rmsnorm
    u16*   MOE   = (u16*)(wsb + 16*MB);              // [8192,512] bf16 (w2 phase)
    u16*   x1h   = (u16*)(wsb + 24*MB);              // [8192,512]; live till final
    u16*   QKb   = (u16*)(wsb + 32*MB);              // [8192,1024]; dead after flash
    u16*   XG    = (u16*)(wsb + 32*MB);              // [8192,512] after QKb dead
    u16*   Hb    = (u16*)(wsb + 40*MB);              // [4096,4096] 32 MB (MoE phase)
    u16*   VbT   = (u16*)(wsb + 48*MB);              // [512,8192]; dead after flash
    u16*   ATT   = (u16*)(wsb + 56*MB);              // [8192,512]; dead after wo

    auto mg128 = [&](const u16* A, int lda, const u16* Bt, int ldb, const float* bias,
                     const float* rs, const u16* glu, void* C, int ldc, u16* C2,
                     int M, int N, int K, int flags){
        dim3 g(N/128, M/128);
        mgemm_kernel<128><<<g, 256, 0, stream>>>(A, lda, Bt, ldb, bias, rs, glu, C, ldc, C2, K, flags);
    };
    auto mg64 = [&](const u16* A, int lda, const u16* Bt, int ldb, const float* bias,
                    const float* rs, const u16* glu, void* C, int ldc, u16* C2,
                    int M, int N, int K, int flags){
        dim3 g(N/128, M/64);
        mgemm_kernel<64><<<g, 256, 0, stream>>>(A, lda, Bt, ldb, bias, rs, glu, C, ldc, C2, K, flags);
    };

    // ---- prepass (re-run every call)
    TJobs JJ; JJ.n = 11;
    auto setj = [&](int i, const float* src, u16* dst, int K, int N, int ldout,
                    int coloff, float scale){
        JJ.j[i] = TJob{src, dst, K, N, ldout, coloff, (K/32)*(N/32), scale};
    };
    setj(0, wq,            wqkvT, 512,  512,  512, 0, QSCALE);   // Q' = wq * 0.125*log2e
    setj(1, wo,            woT,   512,  512,  512, 0, 1.f);
    setj(2, wg,            wgT,   512,  512,  512, 0, 1.f);
    setj(3, fu_w + 512*512,fuBT,  512,  512,  512, 0, 1.f);      // fuB^T
    for (int e = 0; e < 4; ++e){
        setj(4+e, w1 + (size_t)e*512*1024, w1T + (size_t)e*1024*512, 512, 1024, 512, 0, 1.f);
        setj(8+e, w2 + (size_t)e*1024*512, w2Ts + (size_t)e*1024, 1024, 512, 4096, 0, 1.f);
    }
    int nt = 4*256 + 8*512;
    tconv_all_kernel<<<nt, 256, 0, stream>>>(JJ);
    convert_kernel<<<512*512/256, 256, 0, stream>>>(mp_w, mp_wB);
    convert_kernel<<<512*512/256, 256, 0, stream>>>(fu_w, WfuBF);          // fuA rows 0..511
    sgemm_kernel<<<dim3(8,8), 256, 0, stream>>>(wc, wk, wqkvT + 512*512, 32); // Wck^T
    sgemm_kernel<<<dim3(8,8), 256, 0, stream>>>(wc, wv, wqkvT + 1024*512, 32);// Wcv^T
    biasfold_kernel<<<512, 256, 0, stream>>>(fu_b, mp_b, fu_w, fubias);
    qkvbias_kernel<<<1536, 256, 0, stream>>>(fubias, wqkvT, qkvbias);
    // F1 = mp_w @ fuB  -> WfuBF rows 512..1023 (row-major bf16)
    mg64(mp_wB, 512, fuBT, 512, 0, 0, 0, WfuBF + 512*512, 512, 0, 512, 512, 512, 0);
    // Combined W^T: WqkvC[1536,1024] = wqkvT[1536,512] @ WfuBF[1024,512]^T
    mg64(wqkvT, 512, WfuBF, 512, 0, 0, 0, WqkvC, 1024, 0, 1536, 1024, 512, 0);

    // ---- main pipeline
    gatepool_kernel<<<(TOK/16)*512/256, 256, 0, stream>>>(x, XFcat);
    // QKV directly from XFcat (xfu folded): Q'|K -> QKb, V^T -> VbT
    mg64 (XFcat, 1024, WqkvC, 1024, qkvbias, 0, 0, QKb, 1024, VbT, TOK, 1536, 1024, GF_QKV);
    flash_kernel<<<512, 256, 0, stream>>>(QKb, VbT, ATT);
    mg64 (ATT, 512, woT, 512, 0, 0, 0, S3, 512, 0, TOK, 512, 512, 0);        // attn@wo
    rmsnorm_kernel<<<TOK, 256, 0, stream>>>(x, S3, s1, x1h);                 // x1
    router_kernel<<<TOK/4, 256, 0, stream>>>(x1h, wr, br, ROUT);
    mg64 (x1h, 512, wgT, 512, bg, 0, x1h, XG, 512, 0, TOK, 512, 512, GF_GLU);// xg
    for (int h = 0; h < 2; ++h){
        // H[4096,4096] = router-scaled gelu(XG_half @ w1 + b1), all 4 experts wide
        mg128(XG + (size_t)h*4096*512, 512, w1T, 512, b1, ROUT + (size_t)h*4096*4, 0,
              Hb, 4096, 0, 4096, 4096, 512, GF_GELU | GF_RSCOL);
        // MOE_half = H @ w2 (K=4096 single pass, router weights already in H)
        mg64 (Hb, 4096, w2Ts, 4096, 0, 0, 0,
              MOE + (size_t)h*4096*512, 512, 0, 4096, 512, 4096, 0);
    }
    final_kernel<<<TOK, 256, 0, stream>>>(x1h, MOE, ROUT, b2, s2, (float*)d_out);
}

// Round 8
// 583.020 us; speedup vs baseline: 1.0512x; 1.0512x over previous
//
#include <hip/hip_runtime.h>
#include <math.h>

#define B_   4
#define T_   2048
#define D_   512
#define TOK  (B_*T_)      // 8192 tokens
#define TL_  2045         // N_BLOCKS*(T//N_BLOCKS) = 5*409
#define GATE 0.2f         // softmax(...).mean(-1) over same axis == 1/5
#define QSCALE 0.18033688011112043f   // 0.125 * log2(e): S in log2 domain
#define MSPLIT 4096

typedef unsigned short u16;
typedef __attribute__((ext_vector_type(8))) short short8;   // 8 bf16 = 4 VGPRs
typedef __attribute__((ext_vector_type(4))) float f32x4;

static __device__ __forceinline__ u16 f2u(float f){      // fp32 -> bf16 (RNE)
    union { float f; unsigned u; } a; a.f = f;
    unsigned r = a.u + 0x7fffu + ((a.u >> 16) & 1u);
    return (u16)(r >> 16);
}
static __device__ __forceinline__ u16 f2u_t(float f){    // truncating (P in [0,1])
    return (u16)(__float_as_uint(f) >> 16);
}
static __device__ __forceinline__ float u2f(u16 u){
    union { unsigned u; float f; } a; a.u = ((unsigned)u) << 16;
    return a.f;
}
static __device__ __forceinline__ f32x4 mfma16(short8 a, short8 b, f32x4 c){
    return __builtin_amdgcn_mfma_f32_16x16x32_bf16(a, b, c, 0, 0, 0);
}
static __device__ __forceinline__ void glds16(const u16* g, u16* l){
    __builtin_amdgcn_global_load_lds((const __attribute__((address_space(1))) void*)g,
                                     (__attribute__((address_space(3))) void*)l, 16, 0, 0);
}

// ------------------------------------------------------------------
// gate + pool fused: XFcat[:,0:512]=bf16(0.2*x masked), XFcat[:,512:]=bf16(pool)
__global__ __launch_bounds__(256) void gatepool_kernel(
    const float* __restrict__ x, u16* __restrict__ xfcat)
{
    int idx = blockIdx.x*256 + threadIdx.x;
    int d = idx & 511, g = idx >> 9;
    int b = g >> 7, t0 = (g & 127) << 4;
    const float* xp = x + ((size_t)b*2048)*512 + d;
    float v[30];
    #pragma unroll
    for (int j = 0; j < 30; ++j){
        int u = t0 - 7 + j;
        v[j] = (u >= 0 && u < TL_) ? xp[(size_t)u*512] : 0.f;
    }
    float p[31]; p[0] = 0.f;
    #pragma unroll
    for (int j = 0; j < 30; ++j) p[j+1] = p[j] + v[j];
    u16* xc = xfcat + ((size_t)(b*2048 + t0))*1024 + d;
    #pragma unroll
    for (int i = 0; i < 16; ++i){
        int t = t0 + i;
        float sum = p[i+15] - p[i];                 // u in [t-7, t+7]
        int lo = t-7; if (lo < 0) lo = 0;
        int hi = t+7; if (hi > 2047) hi = 2047;
        xc[(size_t)i*1024]       = f2u((t < TL_) ? GATE*v[i+7] : 0.f);
        xc[(size_t)i*1024 + 512] = f2u(GATE * sum / (float)(hi - lo + 1));
    }
}

// ------------------------------------------------------------------
// batched transpose+convert: src fp32 [K,N] -> dst[n*ldout+coloff+k]=bf16(scale*src)
struct TJob { const float* src; u16* dst; int K, N, ldout, coloff, tiles; float scale; };
struct TJobs { TJob j[13]; int n; };

__global__ __launch_bounds__(256) void tconv_all_kernel(TJobs JJ){
    __shared__ float t[32][33];
    int idx = blockIdx.x;
    int jb = 0;
    while (jb < JJ.n - 1 && idx >= JJ.j[jb].tiles){ idx -= JJ.j[jb].tiles; ++jb; }
    TJob J = JJ.j[jb];
    int tX = J.N >> 5;
    int k0 = (idx / tX) * 32, n0 = (idx % tX) * 32;
    int tx = threadIdx.x & 31, ty = threadIdx.x >> 5;
    #pragma unroll
    for (int i = 0; i < 32; i += 8)
        t[ty+i][tx] = J.src[(size_t)(k0+ty+i)*J.N + n0+tx];
    __syncthreads();
    #pragma unroll
    for (int i = 0; i < 32; i += 8)
        J.dst[(size_t)(n0+ty+i)*J.ldout + J.coloff + k0+tx] = f2u(J.scale * t[tx][ty+i]);
}

// fp32 -> bf16 plain convert
__global__ void convert_kernel(const float* __restrict__ in, u16* __restrict__ out){
    int idx = blockIdx.x*256 + threadIdx.x;
    out[idx] = f2u(in[idx]);
}

// fubias[n] = fu_b[n] + sum_d mp_b[d] * fu_w[512+d][n]
__global__ __launch_bounds__(256) void biasfold_kernel(
    const float* __restrict__ fu_b, const float* __restrict__ mp_b,
    const float* __restrict__ fu_w, float* __restrict__ out)
{
    int n = blockIdx.x, tid = threadIdx.x;
    float s = mp_b[tid]*fu_w[(size_t)(512+tid)*512 + n]
            + mp_b[tid+256]*fu_w[(size_t)(768+tid)*512 + n];
    for (int off = 32; off; off >>= 1) s += __shfl_down(s, off);
    __shared__ float ws[4];
    if ((tid & 63) == 0) ws[tid >> 6] = s;
    __syncthreads();
    if (tid == 0) out[n] = fu_b[n] + ws[0]+ws[1]+ws[2]+ws[3];
}

// qkvbias[n] = sum_d fubias[d] * wqkvT[n][d]
__global__ __launch_bounds__(256) void qkvbias_kernel(
    const float* __restrict__ fubias, const u16* __restrict__ wqkvT,
    float* __restrict__ out)
{
    int n = blockIdx.x, tid = threadIdx.x;
    const u16* wp = wqkvT + (size_t)n*512;
    float s = fubias[tid]*u2f(wp[tid]) + fubias[tid+256]*u2f(wp[tid+256]);
    for (int off = 32; off; off >>= 1) s += __shfl_down(s, off);
    __shared__ float ws[4];
    if ((tid & 63) == 0) ws[tid >> 6] = s;
    __syncthreads();
    if (tid == 0) out[n] = ws[0]+ws[1]+ws[2]+ws[3];
}

// small fp32 GEMM, N=512, writes bf16 TRANSPOSED: dstT[n*512 + m] = (A@B)[m][n]
__global__ __launch_bounds__(256) void sgemm_kernel(const float* __restrict__ A,
    const float* __restrict__ B, u16* __restrict__ dstT, int K){
    __shared__ float As[16][65];
    __shared__ float Bs[16][65];
    int tid = threadIdx.x;
    int tx = tid & 15, ty = tid >> 4;
    int m0 = blockIdx.y*64, n0 = blockIdx.x*64;
    int arow = tid >> 2, akq = (tid & 3) * 4;
    int bk = tid >> 4, bn = (tid & 15) * 4;
    float acc[4][4] = {};
    for (int k0 = 0; k0 < K; k0 += 16){
        const float* Ap = A + (size_t)(m0+arow)*K + k0 + akq;
        As[akq+0][arow]=Ap[0]; As[akq+1][arow]=Ap[1];
        As[akq+2][arow]=Ap[2]; As[akq+3][arow]=Ap[3];
        const float* Bp = B + (size_t)(k0+bk)*512 + n0 + bn;
        Bs[bk][bn+0]=Bp[0]; Bs[bk][bn+1]=Bp[1];
        Bs[bk][bn+2]=Bp[2]; Bs[bk][bn+3]=Bp[3];
        __syncthreads();
        #pragma unroll
        for (int kk = 0; kk < 16; ++kk){
            float av[4], bv[4];
            #pragma unroll
            for (int i=0;i<4;++i) av[i]=As[kk][ty*4+i];
            #pragma unroll
            for (int j=0;j<4;++j) bv[j]=Bs[kk][tx*4+j];
            #pragma unroll
            for (int i=0;i<4;++i)
                #pragma unroll
                for (int j=0;j<4;++j) acc[i][j] += av[i]*bv[j];
        }
        __syncthreads();
    }
    #pragma unroll
    for (int i=0;i<4;++i)
        #pragma unroll
        for (int j=0;j<4;++j)
            dstT[(size_t)(n0+tx*4+j)*512 + m0+ty*4+i] = f2u(acc[i][j]);
}

// ------------------------------------------------------------------
// bf16 MFMA GEMM: C[M,N] = op(A @ Bt^T + bias), MTx128 tile, BK=64.
// A/C are split buffers at row MSPLIT: rows >= MSPLIT use A2/CpB (for
// contiguous buffers pass A2 = A + MSPLIT*lda etc).
#define GF_GELU   1
#define GF_ACCUM  2
#define GF_RSCOL  4
#define GF_GLU    8
#define GF_F32OUT 16
#define GF_QKV    32   // n0<1024: plain bf16 -> Cp; n0>=1024: bias + transposed -> Cp2

template<int MT>
__global__ __launch_bounds__(256) void mgemm_kernel(
    const u16* __restrict__ A, const u16* __restrict__ A2, int lda,
    const u16* __restrict__ Bt, int ldb,
    const float* __restrict__ bias, const float* __restrict__ rs,
    const u16* __restrict__ glu, void* __restrict__ Cp, void* __restrict__ CpB,
    int ldc, u16* __restrict__ Cp2, int K, int flags)
{
    constexpr int MI = MT/32;            // m-tiles per wave (16 rows each)
    __shared__ u16 As[MT*64];
    __shared__ u16 Bs[128*64];
    int tid = threadIdx.x;
    int wave = tid >> 6, lane = tid & 63;
    int n16 = lane & 15, quad = lane >> 4;
    int m0 = blockIdx.y * MT, n0 = blockIdx.x * 128;
    int wr = (wave >> 1) * (MT/2), wc = (wave & 1) * 64;

    f32x4 acc[MI][4] = {};

    for (int k0 = 0; k0 < K; k0 += 64){
        #pragma unroll
        for (int i = 0; i < MT/32; ++i){
            int s = i*256 + tid;
            int row = s >> 3, g = (s & 7) ^ (row & 7);
            int rg = m0 + row;
            const u16* Ap = (rg < MSPLIT) ? A + (size_t)rg*lda
                                          : A2 + (size_t)(rg - MSPLIT)*lda;
            glds16(Ap + k0 + g*8, As + (size_t)s*8);
        }
        #pragma unroll
        for (int i = 0; i < 4; ++i){
            int s = i*256 + tid;
            int row = s >> 3, g = (s & 7) ^ (row & 7);
            glds16(Bt + (size_t)(n0+row)*ldb + k0 + g*8, Bs + (size_t)s*8);
        }
        __syncthreads();
        #pragma unroll
        for (int ks = 0; ks < 2; ++ks){
            short8 af[MI], bf[4];
            #pragma unroll
            for (int mi = 0; mi < MI; ++mi){
                int row = wr + mi*16 + n16;
                int g = (ks*4 + quad) ^ (row & 7);
                af[mi] = *(const short8*)&As[row*64 + g*8];
            }
            #pragma unroll
            for (int ni = 0; ni < 4; ++ni){
                int row = wc + ni*16 + n16;
                int g = (ks*4 + quad) ^ (row & 7);
                bf[ni] = *(const short8*)&Bs[row*64 + g*8];
            }
            #pragma unroll
            for (int mi = 0; mi < MI; ++mi)
                #pragma unroll
                for (int ni = 0; ni < 4; ++ni)
                    acc[mi][ni] = mfma16(af[mi], bf[ni], acc[mi][ni]);
        }
        __syncthreads();
    }

    if ((flags & GF_QKV) && n0 >= 1024){
        // V region: bias + store transposed into Cp2 [512, 8192]
        #pragma unroll
        for (int mi = 0; mi < MI; ++mi){
            int row0 = m0 + wr + mi*16 + quad*4;
            #pragma unroll
            for (int ni = 0; ni < 4; ++ni){
                int col = n0 + wc + ni*16 + n16;
                float bb = bias[col];
                ushort4 h4;
                h4.x = f2u(acc[mi][ni][0] + bb); h4.y = f2u(acc[mi][ni][1] + bb);
                h4.z = f2u(acc[mi][ni][2] + bb); h4.w = f2u(acc[mi][ni][3] + bb);
                *(ushort4*)&Cp2[(size_t)(col-1024)*8192 + row0] = h4;
            }
        }
        return;
    }

    #pragma unroll
    for (int mi = 0; mi < MI; ++mi){
        #pragma unroll
        for (int reg = 0; reg < 4; ++reg){
            int row = m0 + wr + mi*16 + quad*4 + reg;
            void*  cb = (row < MSPLIT) ? Cp : CpB;
            size_t rr = (row < MSPLIT) ? row : row - MSPLIT;
            #pragma unroll
            for (int ni = 0; ni < 4; ++ni){
                int col = n0 + wc + ni*16 + n16;
                float v = acc[mi][ni][reg];
                if (bias) v += bias[col];
                if (flags & GF_GELU)  v = 0.5f*v*(1.f + erff(v*0.70710678118f));
                if (flags & GF_GLU)   v = u2f(glu[(size_t)row*512 + col]) / (1.f + __expf(-v));
                if (flags & GF_RSCOL) v *= rs[(size_t)row*4 + (col >> 10)];
                size_t ci = rr*ldc + col;
                if (flags & GF_ACCUM)       ((float*)cb)[ci] += v;
                else if (flags & GF_F32OUT) ((float*)cb)[ci]  = v;
                else                        ((u16*)cb)[ci]    = f2u(v);
            }
        }
    }
}

// ------------------------------------------------------------------
// MFMA flash attention (S^T form), causal, dh=64, 8 heads. PAIRED 64-row
// Q-tiles (qt = 31-p then p) -> every block does exactly 33 k-tile units.
__global__ __launch_bounds__(256) void flash_kernel(
    const u16* __restrict__ QK,   // [8192,1024]: cols 0..511 Q', 512..1023 K
    const u16* __restrict__ VT,   // [512,8192]
    u16* __restrict__ O)          // [8192,512]
{
    int bid = blockIdx.x;
    int p = bid >> 5;                  // 0..15
    int bh = bid & 31;
    int h = bh & 7, b = bh >> 3;
    __shared__ u16 Ks[64*64];
    __shared__ u16 Vt[64*64];
    __shared__ u16 Ps[4][16*64];
    int tid = threadIdx.x;
    int wave = tid >> 6, lane = tid & 63;
    int n16 = lane & 15, quad = lane >> 4;
    size_t btok = (size_t)b*2048;

    for (int ph = 0; ph < 2; ++ph){
        int qt = ph ? p : (31 - p);
        size_t tok0 = btok + qt*64;
        short8 qf[2];
        #pragma unroll
        for (int ks = 0; ks < 2; ++ks)
            qf[ks] = *(const short8*)&QK[(tok0 + wave*16 + n16)*1024
                                         + h*64 + ks*32 + quad*8];
        int qrow = qt*64 + wave*16 + n16;
        float m_st = -3.0e38f, l_st = 0.f;
        f32x4 ov[4] = {};

        for (int kt = 0; kt <= qt; ++kt){
            __syncthreads();
            {   // stage K and V^T tiles (swizzled groups of 8 u16)
                int r = tid >> 2;
                int g0 = (tid & 3) * 2;
                const uint4* kp = (const uint4*)&QK[(btok + kt*64 + r)*1024 + 512 + h*64 + g0*8];
                uint4 ka = kp[0], kb = kp[1];
                *(uint4*)&Ks[r*64 + ((g0  ) ^ (r&7))*8] = ka;
                *(uint4*)&Ks[r*64 + ((g0+1) ^ (r&7))*8] = kb;
                const uint4* vp = (const uint4*)&VT[(size_t)(h*64 + r)*8192 + btok + kt*64 + g0*8];
                uint4 va = vp[0], vb = vp[1];
                *(uint4*)&Vt[r*64 + ((g0  ) ^ (r&7))*8] = va;
                *(uint4*)&Vt[r*64 + ((g0+1) ^ (r&7))*8] = vb;
            }
            __syncthreads();

            f32x4 st[4];
            #pragma unroll
            for (int ct = 0; ct < 4; ++ct){
                f32x4 a = {};
                #pragma unroll
                for (int ks = 0; ks < 2; ++ks){
                    short8 kf = *(const short8*)&Ks[(ct*16+n16)*64 + (((ks*4+quad) ^ (n16&7))*8)];
                    a = mfma16(kf, qf[ks], a);
                }
                st[ct] = a;
            }
            if (kt == qt){                 // diagonal: causal mask
                #pragma unroll
                for (int ct = 0; ct < 4; ++ct){
                    int kb0 = kt*64 + ct*16 + quad*4;
                    #pragma unroll
                    for (int r = 0; r < 4; ++r)
                        if (kb0 + r > qrow) st[ct][r] = -3.0e38f;
                }
            }
            float mx = fmaxf(fmaxf(fmaxf(st[0][0],st[0][1]),fmaxf(st[0][2],st[0][3])),
                       fmaxf(fmaxf(fmaxf(st[1][0],st[1][1]),fmaxf(st[1][2],st[1][3])),
                       fmaxf(fmaxf(fmaxf(st[2][0],st[2][1]),fmaxf(st[2][2],st[2][3])),
                             fmaxf(fmaxf(st[3][0],st[3][1]),fmaxf(st[3][2],st[3][3])))));
            mx = fmaxf(mx, __shfl_xor(mx, 16));
            mx = fmaxf(mx, __shfl_xor(mx, 32));
            float mn = fmaxf(m_st, mx);
            float al = exp2f(m_st - mn);
            m_st = mn;
            float sum = 0.f;
            #pragma unroll
            for (int ct = 0; ct < 4; ++ct)
                #pragma unroll
                for (int r = 0; r < 4; ++r){
                    float pp = exp2f(st[ct][r] - mn);
                    st[ct][r] = pp; sum += pp;
                }
            sum += __shfl_xor(sum, 16);
            sum += __shfl_xor(sum, 32);
            l_st = l_st*al + sum;
            // P store: q-major rows (q = n16), packed b64, truncating cvt
            #pragma unroll
            for (int ct = 0; ct < 4; ++ct){
                ushort4 h4;
                h4.x = f2u_t(st[ct][0]); h4.y = f2u_t(st[ct][1]);
                h4.z = f2u_t(st[ct][2]); h4.w = f2u_t(st[ct][3]);
                int goff = ct*2 + (quad >> 1);
                *(ushort4*)&Ps[wave][n16*64 + ((goff ^ (n16&7))*8) + (quad&1)*4] = h4;
            }
            #pragma unroll
            for (int r = 0; r < 4; ++r){
                float aa = __shfl(al, quad*4 + r);
                #pragma unroll
                for (int dt = 0; dt < 4; ++dt) ov[dt][r] *= aa;
            }
            // O += P V  (same-wave LDS write->read, program order)
            short8 ap[2];
            #pragma unroll
            for (int ks = 0; ks < 2; ++ks)
                ap[ks] = *(const short8*)&Ps[wave][n16*64 + (((ks*4+quad) ^ (n16&7))*8)];
            #pragma unroll
            for (int dt = 0; dt < 4; ++dt)
                #pragma unroll
                for (int ks = 0; ks < 2; ++ks){
                    short8 bv = *(const short8*)&Vt[(dt*16+n16)*64 + (((ks*4+quad) ^ (n16&7))*8)];
                    ov[dt] = mfma16(ap[ks], bv, ov[dt]);
                }
        }
        #pragma unroll
        for (int r = 0; r < 4; ++r){
            float li = __shfl(l_st, quad*4 + r);
            float inv = 1.f / li;
            size_t row = tok0 + wave*16 + quad*4 + r;
            #pragma unroll
            for (int dt = 0; dt < 4; ++dt)
                O[row*512 + h*64 + dt*16 + n16] = f2u(ov[dt][r] * inv);
        }
    }
}

// ------------------------------------------------------------------
// x1h = bf16( rmsnorm(x + y_bf16) * scale )
__global__ __launch_bounds__(256) void rmsnorm_kernel(
    const float* __restrict__ x, const u16* __restrict__ y,
    const float* __restrict__ scale, u16* __restrict__ out)
{
    int tok = blockIdx.x, tid = threadIdx.x;
    size_t base = (size_t)tok * 512;
    float v0 = x[base+tid]     + u2f(y[base+tid]);
    float v1 = x[base+tid+256] + u2f(y[base+tid+256]);
    float ss = v0*v0 + v1*v1;
    for (int off = 32; off; off >>= 1) ss += __shfl_down(ss, off);
    __shared__ float ws[4];
    if ((tid & 63) == 0) ws[tid >> 6] = ss;
    __syncthreads();
    float rstd = rsqrtf((ws[0]+ws[1]+ws[2]+ws[3])*(1.f/512.f) + 1e-6f);
    out[base+tid]     = f2u(scale[tid]     * v0 * rstd);
    out[base+tid+256] = f2u(scale[tid+256] * v1 * rstd);
}

// out_fp32 = rmsnorm(x1h + moe_f32 + ROUT@b2) * scale
__global__ __launch_bounds__(256) void final_kernel(
    const u16* __restrict__ x1, const float* __restrict__ moe,
    const float* __restrict__ rout, const float* __restrict__ b2,
    const float* __restrict__ scale, float* __restrict__ out)
{
    int tok = blockIdx.x, tid = threadIdx.x;
    size_t base = (size_t)tok * 512;
    float r0 = rout[tok*4+0], r1 = rout[tok*4+1], r2 = rout[tok*4+2], r3 = rout[tok*4+3];
    float bb0 = r0*b2[tid]     + r1*b2[512+tid]     + r2*b2[1024+tid]     + r3*b2[1536+tid];
    float bb1 = r0*b2[tid+256] + r1*b2[768+tid]     + r2*b2[1280+tid]     + r3*b2[1792+tid];
    float v0 = u2f(x1[base+tid])     + moe[base+tid]     + bb0;
    float v1 = u2f(x1[base+tid+256]) + moe[base+tid+256] + bb1;
    float ss = v0*v0 + v1*v1;
    for (int off = 32; off; off >>= 1) ss += __shfl_down(ss, off);
    __shared__ float ws[4];
    if ((tid & 63) == 0) ws[tid >> 6] = ss;
    __syncthreads();
    float rstd = rsqrtf((ws[0]+ws[1]+ws[2]+ws[3])*(1.f/512.f) + 1e-6f);
    out[base+tid]     = scale[tid]     * v0 * rstd;
    out[base+tid+256] = scale[tid+256] * v1 * rstd;
}

// router: softmax(x1h @ wr + br), one wave per token
__global__ __launch_bounds__(256) void router_kernel(
    const u16* __restrict__ x1, const float* __restrict__ wr,
    const float* __restrict__ br, float* __restrict__ rout)
{
    int wid = threadIdx.x >> 6, lane = threadIdx.x & 63;
    int tok = blockIdx.x*4 + wid;
    const u16* xp = x1 + (size_t)tok*512;
    float p0=0.f, p1=0.f, p2=0.f, p3=0.f;
    for (int d = lane; d < 512; d += 64){
        float xv = u2f(xp[d]);
        p0 += xv*wr[d*4+0]; p1 += xv*wr[d*4+1];
        p2 += xv*wr[d*4+2]; p3 += xv*wr[d*4+3];
    }
    for (int off = 32; off; off >>= 1){
        p0 += __shfl_down(p0,off); p1 += __shfl_down(p1,off);
        p2 += __shfl_down(p2,off); p3 += __shfl_down(p3,off);
    }
    if (lane == 0){
        p0 += br[0]; p1 += br[1]; p2 += br[2]; p3 += br[3];
        float mx = fmaxf(fmaxf(p0,p1), fmaxf(p2,p3));
        float e0=__expf(p0-mx), e1=__expf(p1-mx), e2=__expf(p2-mx), e3=__expf(p3-mx);
        float inv = 1.f/(e0+e1+e2+e3);
        rout[tok*4+0]=e0*inv; rout[tok*4+1]=e1*inv;
        rout[tok*4+2]=e2*inv; rout[tok*4+3]=e3*inv;
    }
}

// ------------------------------------------------------------------
extern "C" void kernel_launch(void* const* d_in, const int* in_sizes, int n_in,
                              void* d_out, int out_size, void* d_ws, size_t ws_size,
                              hipStream_t stream)
{
    const float* x    = (const float*)d_in[0];
    const float* mp_w = (const float*)d_in[3];
    const float* mp_b = (const float*)d_in[4];
    const float* fu_w = (const float*)d_in[5];
    const float* fu_b = (const float*)d_in[6];
    const float* wc   = (const float*)d_in[7];
    const float* wk   = (const float*)d_in[8];
    const float* wv   = (const float*)d_in[9];
    const float* wq   = (const float*)d_in[10];
    const float* wo   = (const float*)d_in[11];
    const float* s1   = (const float*)d_in[12];
    const float* s2   = (const float*)d_in[13];
    const float* wr   = (const float*)d_in[14];
    const float* br   = (const float*)d_in[15];
    const float* wg   = (const float*)d_in[16];
    const float* bg   = (const float*)d_in[17];
    const float* w1   = (const float*)d_in[18];
    const float* b1   = (const float*)d_in[19];
    const float* w2   = (const float*)d_in[20];
    const float* b2   = (const float*)d_in[21];

    char* wsb = (char*)d_ws;
    const size_t MB = 1024*1024;
    // persistent weights (0..12.3 MB)
    u16*   WqkvC  = (u16*)(wsb + 0);                 // [1536,1024]
    u16*   woT    = (u16*)(wsb + 3*MB);              // [512,512]
    u16*   wgT    = (u16*)(wsb + 3*MB + 512*1024);   // [512,512]
    u16*   w1T    = (u16*)(wsb + 4*MB);              // [4096,512]
    u16*   w2Ts   = (u16*)(wsb + 8*MB);              // [512,4096]
    float* fubias = (float*)(wsb + 12*MB);           // 512
    float* qkvbias= (float*)(wsb + 12*MB + 8192);    // 1536
    float* ROUT   = (float*)(wsb + 12*MB + 32768);   // 8192x4 (128 KB)
    // prepass scratch (dead before gatepool)
    u16*   wqkvT  = (u16*)(wsb + 12*MB + 512*1024);  // [1536,512] 12.5-14
    u16*   fuBT   = (u16*)(wsb + 16*MB);             // [512,512]
    u16*   mp_wB  = (u16*)(wsb + 16*MB + 512*1024);  // [512,512]
    u16*   WfuBF  = (u16*)(wsb + 17*MB);             // [1024,512]
    // rotating big buffers
    u16*   x1h   = (u16*)(wsb + 14*MB);              // 14-22, live till final
    u16*   XFcat = (u16*)(wsb + 16*MB);              // 16-32, dead after QKV
    u16*   XG    = (u16*)(wsb + 22*MB);              // 22-30, live through w1
    u16*   S3    = (u16*)(wsb + 24*MB);              // 24-32, dead after rmsnorm
    u16*   QKb   = (u16*)(wsb + 32*MB);              // 32-48, dead after flash
    float* MOE   = (float*)(wsb + 32*MB);            // 32-48 fp32 (MoE phase)
    u16*   VbT   = (u16*)(wsb + 48*MB);              // 48-56, dead after flash
    u16*   ATT   = (u16*)(wsb + 56*MB);              // 56-64, dead after wo
    u16*   HbA   = (u16*)(wsb + 48*MB);              // 48-80 (MoE phase)
    u16*   HbB   = (u16*)(wsb + 80*MB);              // 80-112 (big-ws path only)
    bool big = ws_size >= (size_t)112*MB;

    auto mg128 = [&](const u16* A, const u16* A2, int lda, const u16* Bt, int ldb,
                     const float* bias, const float* rs, const u16* glu,
                     void* C, void* CB, int ldc, u16* C2, int M, int N, int K, int flags){
        dim3 g(N/128, M/128);
        mgemm_kernel<128><<<g, 256, 0, stream>>>(A, A2, lda, Bt, ldb, bias, rs, glu,
                                                 C, CB, ldc, C2, K, flags);
    };
    auto mg64 = [&](const u16* A, const u16* A2, int lda, const u16* Bt, int ldb,
                    const float* bias, const float* rs, const u16* glu,
                    void* C, void* CB, int ldc, u16* C2, int M, int N, int K, int flags){
        dim3 g(N/128, M/64);
        mgemm_kernel<64><<<g, 256, 0, stream>>>(A, A2, lda, Bt, ldb, bias, rs, glu,
                                                C, CB, ldc, C2, K, flags);
    };

    // ---- prepass (re-run every call)
    TJobs JJ; JJ.n = 12;
    auto setj = [&](int i, const float* src, u16* dst, int K, int N, int ldout,
                    int coloff, float scale){
        JJ.j[i] = TJob{src, dst, K, N, ldout, coloff, (K/32)*(N/32), scale};
    };
    setj(0, wq,            wqkvT, 512,  512,  512, 0, QSCALE);   // Q' = wq*0.125*log2e
    setj(1, wo,            woT,   512,  512,  512, 0, 1.f);
    setj(2, wg,            wgT,   512,  512,  512, 0, 1.f);
    setj(3, fu_w + 512*512,fuBT,  512,  512,  512, 0, 1.f);      // fuB^T
    for (int e = 0; e < 4; ++e){
        setj(4+e, w1 + (size_t)e*512*1024, w1T + (size_t)e*1024*512, 512, 1024, 512, 0, 1.f);
        setj(8+e, w2 + (size_t)e*1024*512, w2Ts + (size_t)e*1024, 1024, 512, 4096, 0, 1.f);
    }
    int nt = 4*256 + 8*512;
    tconv_all_kernel<<<nt, 256, 0, stream>>>(JJ);
    convert_kernel<<<512*512/256, 256, 0, stream>>>(mp_w, mp_wB);
    convert_kernel<<<512*512/256, 256, 0, stream>>>(fu_w, WfuBF);            // fuA rows 0..511
    sgemm_kernel<<<dim3(8,8), 256, 0, stream>>>(wc, wk, wqkvT + 512*512, 32);  // Wck^T
    sgemm_kernel<<<dim3(8,8), 256, 0, stream>>>(wc, wv, wqkvT + 1024*512, 32); // Wcv^T
    biasfold_kernel<<<512, 256, 0, stream>>>(fu_b, mp_b, fu_w, fubias);
    qkvbias_kernel<<<1536, 256, 0, stream>>>(fubias, wqkvT, qkvbias);
    // F1 = mp_w @ fuB -> WfuBF rows 512..1023 (row-major bf16)
    mg64(mp_wB, mp_wB, 512, fuBT, 512, 0, 0, 0,
         WfuBF + 512*512, WfuBF + 512*512, 512, 0, 512, 512, 512, 0);
    // Combined: WqkvC[1536,1024] = wqkvT[1536,512] @ WfuBF[1024,512]^T
    mg64(wqkvT, wqkvT, 512, WfuBF, 512, 0, 0, 0,
         WqkvC, WqkvC, 1024, 0, 1536, 1024, 512, 0);

    // ---- main pipeline
    gatepool_kernel<<<(TOK/16)*512/256, 256, 0, stream>>>(x, XFcat);
    // QKV from XFcat (xfu folded): Q'|K -> QKb, V^T -> VbT.  768 blocks.
    mg128(XFcat, XFcat + (size_t)MSPLIT*1024, 1024, WqkvC, 1024, qkvbias, 0, 0,
          QKb, QKb + (size_t)MSPLIT*1024, 1024, VbT, TOK, 1536, 1024, GF_QKV);
    flash_kernel<<<512, 256, 0, stream>>>(QKb, VbT, ATT);
    mg64 (ATT, ATT + (size_t)MSPLIT*512, 512, woT, 512, 0, 0, 0,
          S3, S3 + (size_t)MSPLIT*512, 512, 0, TOK, 512, 512, 0);            // attn@wo
    rmsnorm_kernel<<<TOK, 256, 0, stream>>>(x, S3, s1, x1h);                 // x1
    router_kernel<<<TOK/4, 256, 0, stream>>>(x1h, wr, br, ROUT);
    mg64 (x1h, x1h + (size_t)MSPLIT*512, 512, wgT, 512, bg, 0, x1h,
          XG, XG + (size_t)MSPLIT*512, 512, 0, TOK, 512, 512, GF_GLU);       // xg
    if (big){
        // w1: one dispatch, M=8192, H split across HbA/HbB.  2048 blocks.
        mg128(XG, XG + (size_t)MSPLIT*512, 512, w1T, 512, b1, ROUT, 0,
              HbA, HbB, 4096, 0, TOK, 4096, 512, GF_GELU | GF_RSCOL);
        // w2: one dispatch, M=8192, K=4096.  512 blocks, 2/CU.
        mg64 (HbA, HbB, 4096, w2Ts, 4096, 0, 0, 0,
              MOE, (float*)MOE + (size_t)MSPLIT*512, 512, 0,
              TOK, 512, 4096, GF_F32OUT);
    } else {
        // fallback (r6 structure): pairwise experts, Hb = HbA [8192,2048]
        for (int p = 0; p < 2; ++p){
            mg128(XG, XG + (size_t)MSPLIT*512, 512, w1T + (size_t)p*2048*512, 512,
                  b1 + p*2048, ROUT + p*2, 0,
                  HbA, HbA + (size_t)MSPLIT*2048, 2048, 0,
                  TOK, 2048, 512, GF_GELU | GF_RSCOL);
            mg64 (HbA, HbA + (size_t)MSPLIT*2048, 2048, w2Ts + p*2048, 4096, 0, 0, 0,
                  MOE, (float*)MOE + (size_t)MSPLIT*512, 512, 0,
                  TOK, 512, 2048, p ? GF_ACCUM : GF_F32OUT);
        }
    }
    final_kernel<<<TOK, 256, 0, stream>>>(x1h, MOE, ROUT, b2, s2, (float*)d_out);
}